// Round 1
// baseline (848.823 us; speedup 1.0000x reference)
//
#include <hip/hip_runtime.h>
#include <hip/hip_bf16.h>

typedef __attribute__((ext_vector_type(8))) __bf16 bf16x8;
typedef __attribute__((ext_vector_type(4))) float f32x4;

#define MDIM 16384  // B*T
#define HDIM 2048
#define IDIM 512
#define ODIM 512
#define CAP 768     // boundary-bin candidate buffer

static __device__ __forceinline__ unsigned short f2bf(float f) {
  unsigned int u = __float_as_uint(f);
  unsigned int r = (u + 0x7fffu + ((u >> 16) & 1u)) >> 16;
  return (unsigned short)r;
}

// ---------------- W_dec f32 -> bf16 ----------------
__global__ void cvt_bf16_kernel(const float* __restrict__ src,
                                unsigned short* __restrict__ dst, int n) {
  int i = (blockIdx.x * 256 + threadIdx.x) * 4;
  if (i >= n) return;
  float4 v = *(const float4*)(src + i);
  unsigned int a = (unsigned int)f2bf(v.x) | ((unsigned int)f2bf(v.y) << 16);
  unsigned int b = (unsigned int)f2bf(v.z) | ((unsigned int)f2bf(v.w) << 16);
  uint2 st; st.x = a; st.y = b;
  *(uint2*)(dst + i) = st;
}

// ---------------- GEMM1: h = x @ W_enc^T + b_enc (f32) ----------------
// v2: 128(M) x 256(N) tile, BK=32, 256 threads, 8x16 micro-tile.
// Rationale: 8x8 micro-tile reads 1.0 B LDS per FMA -> LDS read BW co-saturates
// with VALU (measured VALUBusy 75%). 8x16 reads 0.75 B/FMA -> VALU sole
// bottleneck. k summation order unchanged (bitwise-identical h -> same masks).
__global__ __launch_bounds__(256, 2) void gemm1_kernel(
    const float* __restrict__ x,     // [M, IDIM]
    const float* __restrict__ wenc,  // [HDIM, IDIM]
    const float* __restrict__ benc,  // [HDIM]
    float* __restrict__ h) {         // [M, HDIM]
  __shared__ __align__(16) float As[32][132];  // [k][m], +4 pad
  __shared__ __align__(16) float Bs[32][260];  // [k][n], +4 pad
  const int t = threadIdx.x;
  const int tx = t & 15, ty = t >> 4;
  const int m0 = blockIdx.y * 128;
  const int n0 = blockIdx.x * 256;
  const int rA = t >> 1;          // 0..127 A staging row
  const int kh = (t & 1) * 16;    // k sub-offset (0 or 16)

  const float* pa = x + (size_t)(m0 + rA) * IDIM + kh;
  const float* pb = wenc + (size_t)(n0 + t) * IDIM;

  float acc[8][16];
#pragma unroll
  for (int i = 0; i < 8; ++i)
#pragma unroll
    for (int j = 0; j < 16; ++j) acc[i][j] = 0.f;

  for (int kt = 0; kt < IDIM; kt += 32) {
    // issue global loads before the barrier (overlap prior FMA block)
    float4 a0 = *(const float4*)(pa + kt);
    float4 a1 = *(const float4*)(pa + kt + 4);
    float4 a2 = *(const float4*)(pa + kt + 8);
    float4 a3 = *(const float4*)(pa + kt + 12);
    float4 b0 = *(const float4*)(pb + kt);
    float4 b1 = *(const float4*)(pb + kt + 4);
    float4 b2 = *(const float4*)(pb + kt + 8);
    float4 b3 = *(const float4*)(pb + kt + 12);
    float4 b4 = *(const float4*)(pb + kt + 16);
    float4 b5 = *(const float4*)(pb + kt + 20);
    float4 b6 = *(const float4*)(pb + kt + 24);
    float4 b7 = *(const float4*)(pb + kt + 28);
    __syncthreads();
    {
      const float av[16] = {a0.x, a0.y, a0.z, a0.w, a1.x, a1.y, a1.z, a1.w,
                            a2.x, a2.y, a2.z, a2.w, a3.x, a3.y, a3.z, a3.w};
#pragma unroll
      for (int j = 0; j < 16; ++j) As[kh + j][rA] = av[j];
      const float bv[32] = {b0.x, b0.y, b0.z, b0.w, b1.x, b1.y, b1.z, b1.w,
                            b2.x, b2.y, b2.z, b2.w, b3.x, b3.y, b3.z, b3.w,
                            b4.x, b4.y, b4.z, b4.w, b5.x, b5.y, b5.z, b5.w,
                            b6.x, b6.y, b6.z, b6.w, b7.x, b7.y, b7.z, b7.w};
#pragma unroll
      for (int j = 0; j < 32; ++j) Bs[j][t] = bv[j];
    }
    __syncthreads();
#pragma unroll 8
    for (int k = 0; k < 32; ++k) {
      float4 av0 = *(const float4*)&As[k][ty * 8];
      float4 av1 = *(const float4*)&As[k][ty * 8 + 4];
      float4 bq0 = *(const float4*)&Bs[k][tx * 4];
      float4 bq1 = *(const float4*)&Bs[k][64 + tx * 4];
      float4 bq2 = *(const float4*)&Bs[k][128 + tx * 4];
      float4 bq3 = *(const float4*)&Bs[k][192 + tx * 4];
      float am[8] = {av0.x, av0.y, av0.z, av0.w, av1.x, av1.y, av1.z, av1.w};
      float bm[16] = {bq0.x, bq0.y, bq0.z, bq0.w, bq1.x, bq1.y, bq1.z, bq1.w,
                      bq2.x, bq2.y, bq2.z, bq2.w, bq3.x, bq3.y, bq3.z, bq3.w};
#pragma unroll
      for (int i = 0; i < 8; ++i)
#pragma unroll
        for (int j = 0; j < 16; ++j) acc[i][j] += am[i] * bm[j];
    }
  }
  float4 be0 = *(const float4*)(benc + n0 + tx * 4);
  float4 be1 = *(const float4*)(benc + n0 + 64 + tx * 4);
  float4 be2 = *(const float4*)(benc + n0 + 128 + tx * 4);
  float4 be3 = *(const float4*)(benc + n0 + 192 + tx * 4);
  float bb[16] = {be0.x, be0.y, be0.z, be0.w, be1.x, be1.y, be1.z, be1.w,
                  be2.x, be2.y, be2.z, be2.w, be3.x, be3.y, be3.z, be3.w};
#pragma unroll
  for (int i = 0; i < 8; ++i) {
    int m = m0 + ty * 8 + i;
    float* hrow = h + (size_t)m * HDIM + n0;
#pragma unroll
    for (int q = 0; q < 4; ++q) {
      float4 s = {acc[i][q * 4 + 0] + bb[q * 4 + 0],
                  acc[i][q * 4 + 1] + bb[q * 4 + 1],
                  acc[i][q * 4 + 2] + bb[q * 4 + 2],
                  acc[i][q * 4 + 3] + bb[q * 4 + 3]};
      *(float4*)(hrow + q * 64 + tx * 4) = s;
    }
  }
}

// ---------------- selection v3: histogram radix-select (verified round 2) -----
__global__ __launch_bounds__(256) void select_kernel(
    float* __restrict__ hbuf,           // in: raw h [M,HDIM]; out: mask_prev_new
    const int* __restrict__ maskp,      // [M, HDIM]
    unsigned short* __restrict__ hs) {  // out: h*mask_share as bf16 [M,HDIM]
  const int row = blockIdx.x;
  const int t = threadIdx.x;
  const int lane = t & 63;
  const int w = t >> 6;
  __shared__ int hist[4096];
  __shared__ unsigned int cand512[CAP];
  __shared__ unsigned int cand256[CAP];
  __shared__ int scal[16];
  __shared__ int n512, n256;

  float* hrow = hbuf + (size_t)row * HDIM;
  const int* mrow = maskp + (size_t)row * HDIM;
  float hv[8];
  *(float4*)&hv[0] = *(const float4*)(hrow + t * 8);
  *(float4*)&hv[4] = *(const float4*)(hrow + t * 8 + 4);
  int4 mp0 = *(const int4*)(mrow + t * 8);
  int4 mp1 = *(const int4*)(mrow + t * 8 + 4);
  int mm[8] = {mp0.x, mp0.y, mp0.z, mp0.w, mp1.x, mp1.y, mp1.z, mp1.w};
#pragma unroll
  for (int i = 0; i < 8; ++i) hv[i] = (mm[i] > 0) ? 0.f : hv[i];
  unsigned int key[8];
#pragma unroll
  for (int i = 0; i < 8; ++i) key[i] = __float_as_uint(hv[i] * hv[i]);

#pragma unroll
  for (int i = 0; i < 16; ++i) hist[t + i * 256] = 0;
  if (t == 0) {
    n512 = 0; n256 = 0;
    scal[0] = 0; scal[1] = 0x40000000;
    scal[2] = 0; scal[3] = 0x40000000;
  }
  __syncthreads();
#pragma unroll
  for (int i = 0; i < 8; ++i)
    if (key[i]) atomicAdd(&hist[key[i] >> 20], 1);
  __syncthreads();

  if (w == 0) {
    const int base = lane * 64;
    int s = 0;
#pragma unroll
    for (int i = 0; i < 64; i += 4) {
      int4 hh = *(const int4*)&hist[base + i];
      s += hh.x + hh.y + hh.z + hh.w;
    }
    int rs = s;
#pragma unroll
    for (int d = 1; d < 64; d <<= 1) {
      int o = __shfl_down(rs, d, 64);
      rs += (lane + d < 64) ? o : 0;
    }
    int c = rs - s;
    for (int i = 60; i >= 0; i -= 4) {
      int4 hh = *(const int4*)&hist[base + i];
      int q[4] = {hh.x, hh.y, hh.z, hh.w};
#pragma unroll
      for (int j = 3; j >= 0; --j) {
        int hc = q[j];
        if (c < 512 && c + hc >= 512) { scal[0] = base + i + j; scal[1] = 512 - c; }
        if (c < 256 && c + hc >= 256) { scal[2] = base + i + j; scal[3] = 256 - c; }
        c += hc;
      }
    }
  }
  __syncthreads();
  const int b512 = scal[0], b256 = scal[2];
#pragma unroll
  for (int i = 0; i < 8; ++i) {
    if (key[i]) {
      int bin = (int)(key[i] >> 20);
      if (bin == b512) { int p = atomicAdd(&n512, 1); if (p < CAP) cand512[p] = key[i]; }
      if (bin == b256) { int p = atomicAdd(&n256, 1); if (p < CAP) cand256[p] = key[i]; }
    }
  }
  __syncthreads();

  if (w < 2) {
    const unsigned int bb = (unsigned int)scal[w * 2];
    const int r = scal[w * 2 + 1];
    const unsigned int* cand = w ? cand256 : cand512;
    int C = w ? n256 : n512;
    C = (C < CAP) ? C : CAP;
    unsigned int v = 0;
    if (r <= C) {
      v = bb << 20;
      for (int bit = 19; bit >= 0; --bit) {
        unsigned int cth = v | (1u << bit);
        int cnt = 0;
        for (int p = lane; p < C; p += 64) cnt += (cand[p] >= cth) ? 1 : 0;
#pragma unroll
        for (int d = 1; d < 64; d <<= 1) cnt += __shfl_xor(cnt, d, 64);
        if (cnt >= r) v = cth;
      }
    }
    if (lane == 0) scal[4 + w] = (int)v;
  }
  __syncthreads();
  const unsigned int v512 = (unsigned int)scal[4];
  const unsigned int v256 = (unsigned int)scal[5];

  int g = 0;
#pragma unroll
  for (int i = 0; i < 8; ++i) {
    g += (key[i] > v512) ? 1 : 0;
    g += (key[i] > v256) ? (1 << 16) : 0;
  }
#pragma unroll
  for (int d = 1; d < 64; d <<= 1) g += __shfl_xor(g, d, 64);
  if (lane == 0) scal[8 + w] = g;
  __syncthreads();
  g = scal[8] + scal[9] + scal[10] + scal[11];
  const int r512 = 512 - (g & 0xffff);
  const int r256 = 256 - (g >> 16);

  int tc = 0;
#pragma unroll
  for (int i = 0; i < 8; ++i) {
    tc += (key[i] == v512) ? 1 : 0;
    tc += (key[i] == v256) ? (1 << 16) : 0;
  }
  int sc = tc;
#pragma unroll
  for (int d = 1; d < 64; d <<= 1) {
    int o = __shfl_up(sc, d, 64);
    if (lane >= d) sc += o;
  }
  if (lane == 63) scal[12 + w] = sc;
  __syncthreads();
  int excl = sc - tc;
  for (int i = 0; i < w; ++i) excl += scal[12 + i];
  int run512 = excl & 0xffff;
  int run256 = (excl >> 16) & 0xffff;

  float mpn[8];
  unsigned int hb[4];
#pragma unroll
  for (int i = 0; i < 8; ++i) {
    bool share, cur;
    if (key[i] > v512) share = true;
    else if (key[i] == v512) { share = (run512 < r512); run512++; }
    else share = false;
    if (key[i] > v256) cur = true;
    else if (key[i] == v256) { cur = (run256 < r256); run256++; }
    else cur = false;
    mpn[i] = (float)mm[i] + (cur ? 1.0f : 0.0f);
    unsigned short bbits = f2bf(share ? hv[i] : 0.0f);
    if (i & 1) hb[i >> 1] |= ((unsigned int)bbits << 16);
    else hb[i >> 1] = (unsigned int)bbits;
  }
  float4 s0 = {mpn[0], mpn[1], mpn[2], mpn[3]};
  float4 s1 = {mpn[4], mpn[5], mpn[6], mpn[7]};
  *(float4*)(hrow + t * 8) = s0;
  *(float4*)(hrow + t * 8 + 4) = s1;
  uint4 hstore = {hb[0], hb[1], hb[2], hb[3]};
  *(uint4*)(hs + (size_t)row * HDIM + t * 8) = hstore;
}

// ---------------- GEMM2: out = hs @ W_dec^T + b_dec (bf16 MFMA) ----------------
// 64x128 (MxN) tile, BK=32, 256 thr / 4 waves in 2x2; wave = 32x64 (2x4 subtiles).
__global__ __launch_bounds__(256) void gemm2_kernel(
    const unsigned short* __restrict__ A,  // hs bf16 [M, HDIM]
    const unsigned short* __restrict__ B,  // W_dec bf16 [ODIM, HDIM]
    const float* __restrict__ bdec,        // [ODIM]
    float* __restrict__ out) {             // [M, ODIM] f32
  __shared__ __align__(16) __bf16 As[64 * 32];
  __shared__ __align__(16) __bf16 Bs[128 * 32];
  const int t = threadIdx.x;
  const int lane = t & 63;
  const int w = t >> 6;
  const int wm = w >> 1, wn = w & 1;
  const int m0 = blockIdx.y * 64;
  const int n0 = blockIdx.x * 128;
  const int r = t >> 2;          // staging row 0..63
  const int k8 = (t & 3) * 8;

  f32x4 acc[2][4];
#pragma unroll
  for (int i = 0; i < 2; ++i)
#pragma unroll
    for (int j = 0; j < 4; ++j) acc[i][j] = (f32x4){0.f, 0.f, 0.f, 0.f};

  const int la = lane & 15;
  const int kq = (lane >> 4) * 8;

  for (int kt = 0; kt < HDIM; kt += 32) {
    uint4 a0 = *(const uint4*)(A + (size_t)(m0 + r) * HDIM + kt + k8);
    uint4 b0 = *(const uint4*)(B + (size_t)(n0 + r) * HDIM + kt + k8);
    uint4 b1 = *(const uint4*)(B + (size_t)(n0 + 64 + r) * HDIM + kt + k8);
    __syncthreads();
    *(uint4*)&As[r * 32 + k8] = a0;
    *(uint4*)&Bs[r * 32 + k8] = b0;
    *(uint4*)&Bs[(64 + r) * 32 + k8] = b1;
    __syncthreads();
    bf16x8 af[2], bg[4];
#pragma unroll
    for (int mi = 0; mi < 2; ++mi)
      af[mi] = *(const bf16x8*)&As[(wm * 32 + mi * 16 + la) * 32 + kq];
#pragma unroll
    for (int ni = 0; ni < 4; ++ni)
      bg[ni] = *(const bf16x8*)&Bs[(wn * 64 + ni * 16 + la) * 32 + kq];
#pragma unroll
    for (int mi = 0; mi < 2; ++mi)
#pragma unroll
      for (int ni = 0; ni < 4; ++ni)
        acc[mi][ni] = __builtin_amdgcn_mfma_f32_16x16x32_bf16(
            af[mi], bg[ni], acc[mi][ni], 0, 0, 0);
  }
  // C/D: col = lane&15, row = (lane>>4)*4 + reg
  const int rq = (lane >> 4) * 4;
#pragma unroll
  for (int mi = 0; mi < 2; ++mi) {
#pragma unroll
    for (int ni = 0; ni < 4; ++ni) {
      int n = n0 + wn * 64 + ni * 16 + la;
      float bd = bdec[n];
#pragma unroll
      for (int rr = 0; rr < 4; ++rr) {
        int m = m0 + wm * 32 + mi * 16 + rq + rr;
        out[(size_t)m * ODIM + n] = acc[mi][ni][rr] + bd;
      }
    }
  }
}

extern "C" void kernel_launch(void* const* d_in, const int* in_sizes, int n_in,
                              void* d_out, int out_size, void* d_ws, size_t ws_size,
                              hipStream_t stream) {
  const float* x = (const float*)d_in[0];
  const int* mask_prev = (const int*)d_in[1];
  const float* W_enc = (const float*)d_in[2];
  const float* b_enc = (const float*)d_in[3];
  const float* W_dec = (const float*)d_in[4];
  const float* b_dec = (const float*)d_in[5];

  float* out = (float*)d_out;
  float* hbuf = out + (size_t)MDIM * ODIM;          // h / mask_prev_new slot
  unsigned short* hs = (unsigned short*)d_ws;       // [M, HDIM] bf16
  unsigned short* wdec = hs + (size_t)MDIM * HDIM;  // [ODIM, HDIM] bf16

  cvt_bf16_kernel<<<dim3((ODIM * HDIM) / (256 * 4)), dim3(256), 0, stream>>>(
      W_dec, wdec, ODIM * HDIM);
  gemm1_kernel<<<dim3(HDIM / 256, MDIM / 128), dim3(256), 0, stream>>>(
      x, W_enc, b_enc, hbuf);
  select_kernel<<<dim3(MDIM), dim3(256), 0, stream>>>(hbuf, mask_prev, hs);
  gemm2_kernel<<<dim3(ODIM / 128, MDIM / 64), dim3(256), 0, stream>>>(
      hs, wdec, b_dec, out);
}